// Round 4
// baseline (259.523 us; speedup 1.0000x reference)
//
#include <hip/hip_runtime.h>

#define HDIM 512
#define HALF 256
#define NRELS 12
#define NBASES 8
#define NLAYERS 12
#define NBLOCKS 2
#define NHEADS 8
#define NENTS 50000
#define TXTD 768
#define BATCH 32
#define ELEN 50
#define SLEN 128
#define NPOS (BATCH * ELEN)   // 1600

typedef unsigned short u16;
typedef __attribute__((ext_vector_type(8))) __bf16 bf16x8;
typedef __attribute__((ext_vector_type(4))) float f32x4;

__device__ __forceinline__ u16 f2bf(float f) {
    unsigned int u = __float_as_uint(f);
    unsigned int r = (u + 0x7FFFu + ((u >> 16) & 1u)) >> 16;
    return (u16)r;
}
__device__ __forceinline__ float bf2f(u16 v) {
    return __uint_as_float(((unsigned int)v) << 16);
}

#define ASYNC_COPY16(g, l)                                                              \
    __builtin_amdgcn_global_load_lds((const __attribute__((address_space(1))) void*)(g), \
                                     (__attribute__((address_space(3))) unsigned int*)(l), 16, 0, 0)

// ---------------------------------------------------------------------------
// 0) init: zero agg/cnt/ZB/nuniq/loss, map=-1
// ---------------------------------------------------------------------------
__global__ void init_kernel(float* __restrict__ agg, float* __restrict__ cnt,
                            int* __restrict__ map, int* __restrict__ nuniq,
                            float* __restrict__ zb, float* __restrict__ out_last) {
    int tid = blockIdx.x * blockDim.x + threadIdx.x;
    int nt = gridDim.x * blockDim.x;
    float4 z4 = {0.f, 0.f, 0.f, 0.f};
    for (int i = tid; i < (NPOS * NRELS * HALF) / 4; i += nt) ((float4*)agg)[i] = z4;
    for (int i = tid; i < (NPOS * NRELS) / 4; i += nt) ((float4*)cnt)[i] = z4;
    int4 m4 = {-1, -1, -1, -1};
    for (int i = tid; i < NENTS / 4; i += nt) ((int4*)map)[i] = m4;
    for (int i = tid; i < 1536; i += nt) zb[i] = 0.f;
    if (tid == 0) { *nuniq = 0; *out_last = 0.f; }
}

// ---------------------------------------------------------------------------
// 1) Dedupe entity ids
// ---------------------------------------------------------------------------
__global__ void dedup_kernel(const int* __restrict__ eid, int* __restrict__ map,
                             int* __restrict__ uniq, int* __restrict__ nuniq) {
    int i = blockIdx.x * blockDim.x + threadIdx.x;
    if (i >= NPOS) return;
    int n = eid[i];
    int old = atomicCAS(&map[n], -1, -2);
    if (old == -1) {
        int idx = atomicAdd(nuniq, 1);
        uniq[idx] = n;
        __threadfence();
        map[n] = idx;
    }
}

// ---------------------------------------------------------------------------
// 2) mid: {qct | gather_txim | edge_scatter} packed by block range (independent)
// ---------------------------------------------------------------------------
__global__ __launch_bounds__(256) void mid_kernel(
    // qct
    const float* __restrict__ tok, const float* __restrict__ cq_w, const float* __restrict__ cq_b,
    const float* __restrict__ kgb, const float* __restrict__ imb, const float* __restrict__ txb,
    u16* __restrict__ qbf, float* __restrict__ CT,
    // gather
    const int* __restrict__ uniq, const int* __restrict__ nuniq,
    const float* __restrict__ txi, const float* __restrict__ imi,
    u16* __restrict__ TXIN, u16* __restrict__ IMIN,
    // edge
    const int* __restrict__ ei, const int* __restrict__ et, const int* __restrict__ map,
    const float* __restrict__ x, float* __restrict__ agg, float* __restrict__ cnt, int E) {
    __shared__ float mv[HDIM];
    __shared__ float red[256];
    int blk = blockIdx.x;
    int t = threadIdx.x;
    if (blk < 32) {
        // ---- qct for batch b = blk ----
        int b = blk;
        for (int col = t; col < HDIM; col += 256) {
            float s = 0.f;
            for (int si = 0; si < SLEN; ++si) s += tok[((size_t)b * SLEN + si) * HDIM + col];
            mv[col] = s * (1.0f / SLEN);
        }
        __syncthreads();
        float a0 = cq_b[t];
        for (int i = 0; i < HDIM; ++i) a0 += mv[i] * cq_w[(size_t)i * HDIM + t];
        qbf[(size_t)b * HDIM + t] = f2bf(a0);
        float a1 = cq_b[t + 256];
        for (int i = 0; i < HDIM; ++i) a1 += mv[i] * cq_w[(size_t)i * HDIM + t + 256];
        qbf[(size_t)b * HDIM + t + 256] = f2bf(a1);
        const float* bz[3] = {kgb, imb, txb};
        for (int z = 0; z < 3; ++z) {
            red[t] = a0 * bz[z][t] + a1 * bz[z][t + 256];
            __syncthreads();
            for (int s = 128; s; s >>= 1) { if (t < s) red[t] += red[t + s]; __syncthreads(); }
            if (t == 0) CT[z * BATCH + b] = red[0];
            __syncthreads();
        }
    } else if (blk < 320) {
        // ---- gather text/image rows (288 blocks, persistent over 1600 u) ----
        if (t >= TXTD / 4) return;
        int nu = *nuniq;
        for (int u = blk - 32; u < NPOS; u += 288) {
            if (u >= nu) {
                ushort4 z = {0, 0, 0, 0};
                ((ushort4*)(TXIN + (size_t)u * TXTD))[t] = z;
                ((ushort4*)(IMIN + (size_t)u * TXTD))[t] = z;
                continue;
            }
            int n = uniq[u];
            float4 v = ((const float4*)(txi + (size_t)n * TXTD))[t];
            ushort4 o;
            o.x = f2bf(v.x); o.y = f2bf(v.y); o.z = f2bf(v.z); o.w = f2bf(v.w);
            ((ushort4*)(TXIN + (size_t)u * TXTD))[t] = o;
            v = ((const float4*)(imi + (size_t)n * TXTD))[t];
            o.x = f2bf(v.x); o.y = f2bf(v.y); o.z = f2bf(v.z); o.w = f2bf(v.w);
            ((ushort4*)(IMIN + (size_t)u * TXTD))[t] = o;
        }
    } else {
        // ---- edge scatter (704 blocks = 2816 waves) ----
        const int* __restrict__ srcA = ei;
        const int* __restrict__ dstA = ei + E;
        int lane = t & 63;
        int wid = (blk - 320) * 4 + (t >> 6);
        int nw = 704 * 4;
        for (int base = wid * 64; base < E; base += nw * 64) {
            int e = base + lane;
            int c = -1, rel = 0, src = 0;
            if (e < E) {
                int d = dstA[e];
                c = map[d];
                if (c >= 0) { rel = et[e]; src = srcA[e]; }
            }
            unsigned long long m = __ballot(c >= 0);
            while (m) {
                int bit = __builtin_ctzll(m);
                m &= m - 1;
                int cc = __shfl(c, bit);
                int rr = __shfl(rel, bit);
                int ss = __shfl(src, bit);
                float4 v = ((const float4*)(x + (size_t)ss * HALF))[lane];
                float* dest = agg + ((size_t)cc * NRELS + rr) * HALF + lane * 4;
                atomicAdd(dest + 0, v.x);
                atomicAdd(dest + 1, v.y);
                atomicAdd(dest + 2, v.z);
                atomicAdd(dest + 3, v.w);
                if (lane == 0) atomicAdd(&cnt[cc * NRELS + rr], 1.0f);
            }
        }
    }
}

// ---------------------------------------------------------------------------
// 3) Build MBX[u, 2304] bf16
// ---------------------------------------------------------------------------
__global__ void build_mbx_kernel(const float* __restrict__ agg, const float* __restrict__ cnt,
                                 const int* __restrict__ uniq, const int* __restrict__ nuniq,
                                 const float* __restrict__ comp, const float* __restrict__ x,
                                 u16* __restrict__ MBX) {
    int u = blockIdx.x;
    int i = threadIdx.x;  // 256 threads
    __shared__ float sc[NRELS * NBASES];
    if (i < NRELS * NBASES) sc[i] = comp[i];
    __syncthreads();
    u16* row = MBX + (size_t)u * (NBASES * HALF + HALF);
    int nu = *nuniq;
    if (u >= nu) {
        for (int b = 0; b < NBASES + 1; ++b) row[b * HALF + i] = 0;
        return;
    }
    float mr[NRELS];
    for (int r = 0; r < NRELS; ++r) {
        float c = cnt[u * NRELS + r];
        float inv = 1.f / fmaxf(c, 1.f);
        mr[r] = agg[((size_t)u * NRELS + r) * HALF + i] * inv;
    }
    #pragma unroll
    for (int b = 0; b < NBASES; ++b) {
        float a = 0.f;
        #pragma unroll
        for (int r = 0; r < NRELS; ++r) a += sc[r * NBASES + b] * mr[r];
        row[b * HALF + i] = f2bf(a);
    }
    row[NBASES * HALF + i] = f2bf(x[(size_t)uniq[u] * HALF + i]);
}

// ---------------------------------------------------------------------------
// 4) ONE weight-prep kernel (8 transposes + 3 converts)
// ---------------------------------------------------------------------------
struct PrepArgs {
    const float* src[11];
    u16* dst[11];
};
__global__ __launch_bounds__(256) void prep_kernel(PrepArgs a) {
    constexpr int KK[8]   = {2048, 256, 256, 768, 768, 512, 256, 512};
    constexpr int NN[8]   = {256, 256, 512, 512, 512, 256, 512, 12288};
    constexpr int LDT[8]  = {2304, 2304, 256, 768, 768, 512, 256, 512};
    constexpr int KOFF[8] = {0, 2048, 0, 0, 0, 0, 0, 0};
    constexpr int BASE[12] = {0, 512, 576, 704, 1088, 1472, 1600, 1728, 7872, 8128, 8384, 8640};
    __shared__ u16 tb[32][33];
    int bid = blockIdx.x;
    int op = 0;
    #pragma unroll
    for (int i = 1; i < 11; ++i)
        if (bid >= BASE[i]) op = i;
    int idx = bid - BASE[op];
    if (op < 8) {
        int Nv = 0, ldt = 0, koff = 0;
        #pragma unroll
        for (int i = 0; i < 8; ++i)
            if (op == i) { Nv = NN[i]; ldt = LDT[i]; koff = KOFF[i]; (void)KK[i]; }
        int ncols = Nv / 32;
        int n0 = (idx % ncols) * 32, k0 = (idx / ncols) * 32;
        const float* W = a.src[op];
        u16* WT = a.dst[op];
        int tx = threadIdx.x & 31, ty = threadIdx.x >> 5;
        #pragma unroll
        for (int i = ty; i < 32; i += 8)
            tb[i][tx] = f2bf(W[(size_t)(k0 + i) * Nv + n0 + tx]);
        __syncthreads();
        #pragma unroll
        for (int i = ty; i < 32; i += 8)
            WT[(size_t)(n0 + i) * ldt + koff + k0 + tx] = tb[tx][i];
    } else {
        int e = idx * 1024 + threadIdx.x * 4;
        float4 v = *(const float4*)(a.src[op] + e);
        ushort4 o;
        o.x = f2bf(v.x); o.y = f2bf(v.y); o.z = f2bf(v.z); o.w = f2bf(v.w);
        *(ushort4*)(a.dst[op] + e) = o;
    }
}

// ---------------------------------------------------------------------------
// MFMA bf16 GEMM body
// ---------------------------------------------------------------------------
template <int BM, int BN, int WM, int WN, int ACT, bool RES, bool SCATTER, bool OUTBF>
__device__ __forceinline__ void gemm_body(const u16* __restrict__ A, const u16* __restrict__ BT,
                                          const float* __restrict__ bias, const float* __restrict__ res,
                                          void* __restrict__ Cout, int M, int N, int K,
                                          int bx, int by) {
    constexpr int MF = WM / 16, NF = WN / 16;
    constexpr int NWC = BN / WN;
    __shared__ u16 ldsA[BM][64];
    __shared__ u16 ldsB[BN][64];
    const int tid = threadIdx.x;
    const int lane = tid & 63;
    const int wv = tid >> 6;
    const int m0 = by * BM;
    const int n0 = bx * BN;
    const int wr = wv / NWC, wc = wv % NWC;
    const int srow = lane >> 3;
    const int sslot = lane & 7;

    f32x4 acc[MF][NF];
    #pragma unroll
    for (int i = 0; i < MF; ++i)
        #pragma unroll
        for (int j = 0; j < NF; ++j)
            #pragma unroll
            for (int r = 0; r < 4; ++r) acc[i][j][r] = 0.f;

    for (int k0 = 0; k0 < K; k0 += 64) {
        #pragma unroll
        for (int i = 0; i < BM / 32; ++i) {
            int R = wv * (BM / 4) + i * 8 + srow;
            int gm = m0 + R;
            gm = gm < M ? gm : M - 1;
            int s = sslot ^ (R & 7);
            ASYNC_COPY16(A + (size_t)gm * K + k0 + s * 8, &ldsA[wv * (BM / 4) + i * 8][0]);
        }
        #pragma unroll
        for (int i = 0; i < BN / 32; ++i) {
            int R = wv * (BN / 4) + i * 8 + srow;
            int s = sslot ^ (R & 7);
            ASYNC_COPY16(BT + (size_t)(n0 + R) * K + k0 + s * 8, &ldsB[wv * (BN / 4) + i * 8][0]);
        }
        __syncthreads();
        #pragma unroll
        for (int ks = 0; ks < 2; ++ks) {
            bf16x8 af[MF], bf[NF];
            int kg = ks * 4 + (lane >> 4);
            int rl = lane & 15;
            #pragma unroll
            for (int i = 0; i < MF; ++i) {
                int row = wr * WM + i * 16 + rl;
                af[i] = *(const bf16x8*)&ldsA[row][(kg ^ (row & 7)) * 8];
            }
            #pragma unroll
            for (int j = 0; j < NF; ++j) {
                int row = wc * WN + j * 16 + rl;
                bf[j] = *(const bf16x8*)&ldsB[row][(kg ^ (row & 7)) * 8];
            }
            #pragma unroll
            for (int i = 0; i < MF; ++i)
                #pragma unroll
                for (int j = 0; j < NF; ++j)
                    acc[i][j] = __builtin_amdgcn_mfma_f32_16x16x32_bf16(af[i], bf[j], acc[i][j], 0, 0, 0);
        }
        __syncthreads();
    }

    const int rl = lane & 15, rg = lane >> 4;
    #pragma unroll
    for (int i = 0; i < MF; ++i) {
        #pragma unroll
        for (int j = 0; j < NF; ++j) {
            int col = n0 + wc * WN + j * 16 + rl;
            float bv = bias[col];
            #pragma unroll
            for (int r = 0; r < 4; ++r) {
                int row = m0 + wr * WM + i * 16 + rg * 4 + r;
                if (row >= M) continue;
                float x = acc[i][j][r] + bv;
                if (ACT == 1) x = fmaxf(x, 0.f);
                if (RES) x += res[(size_t)row * N + col];
                if (SCATTER) {
                    int layer = col >> 10, blk = (col >> 9) & 1, head = (col >> 6) & 7, hd = col & 63;
                    int bb = row / ELEN, ll = row - bb * ELEN;
                    size_t oi = (((((size_t)layer * NBLOCKS + blk) * BATCH + bb) * NHEADS + head) * ELEN + ll) * 64 + hd;
                    ((float*)Cout)[oi] = x;
                } else if (OUTBF) {
                    ((u16*)Cout)[(size_t)row * N + col] = f2bf(x);
                } else {
                    ((float*)Cout)[(size_t)row * N + col] = x;
                }
            }
        }
    }
}

template <int BM, int BN, int WM, int WN, int ACT, bool RES, bool SCATTER, bool OUTBF>
__global__ __launch_bounds__(256)
void mfma_gemm(const u16* __restrict__ A, const u16* __restrict__ BT,
               const float* __restrict__ bias, const float* __restrict__ res,
               void* __restrict__ Cout, int M, int N, int K) {
    gemm_body<BM, BN, WM, WN, ACT, RES, SCATTER, OUTBF>(A, BT, bias, res, Cout, M, N, K,
                                                        blockIdx.x, blockIdx.y);
}

// ---------------------------------------------------------------------------
// 5) hetero {QP (24 tiles) + RG (100 tiles)} in one launch
// ---------------------------------------------------------------------------
__global__ __launch_bounds__(256) void gemmA_kernel(
    const u16* __restrict__ QB, const u16* __restrict__ KGW, const float* __restrict__ ZB,
    float* __restrict__ QP, const u16* __restrict__ MBX, const u16* __restrict__ BBT,
    const float* __restrict__ rgcn_bias, u16* __restrict__ RG) {
    if (blockIdx.x < 24) {
        gemm_body<64, 64, 32, 32, 0, false, false, false>(QB, KGW, ZB, nullptr, QP,
                                                          BATCH, 1536, HDIM, blockIdx.x, 0);
    } else {
        int idx = blockIdx.x - 24;
        gemm_body<64, 64, 32, 32, 0, false, false, true>(MBX, BBT, rgcn_bias, nullptr, RG,
                                                         NPOS, HALF, 2304, idx % 4, idx / 4);
    }
}

// 6) batched 3-way projection
struct Proj3Args {
    const u16* A[3];
    const u16* B[3];
    const float* bias[3];
    u16* C[3];
    int K[3];
};
__global__ __launch_bounds__(256) void proj3_kernel(Proj3Args a) {
    int z = blockIdx.z;
    gemm_body<64, 64, 32, 32, 0, false, false, true>(a.A[z], a.B[z], a.bias[z], nullptr,
                                                     a.C[z], NPOS, HDIM, a.K[z],
                                                     blockIdx.x, blockIdx.y);
}

// ---------------------------------------------------------------------------
// 7) tail: fusion + P1 + H fused. 32 rows/block, 50 blocks, 4 waves.
//    FUS kept in LDS (bf16, padded stride), P1 in LDS; B-frags read direct
//    from L2-hot global weights.
// ---------------------------------------------------------------------------
__global__ __launch_bounds__(256) void tail_kernel(
    const int* __restrict__ eid, const int* __restrict__ map,
    const u16* __restrict__ KGU, const u16* __restrict__ IMU, const u16* __restrict__ TXU,
    const float* __restrict__ qp, const float* __restrict__ ct,
    const u16* __restrict__ W1T, const float* __restrict__ pp1_b1,
    const u16* __restrict__ W2T, const float* __restrict__ pp1_b2,
    u16* __restrict__ Hh) {
    __shared__ u16 FUS[32][520];   // row stride 1040B -> bank shift 4/row: conflict-free enough
    __shared__ u16 P1s[32][264];
    const int bm0 = blockIdx.x * 32;
    const int lane = threadIdx.x & 63;
    const int wv = threadIdx.x >> 6;

    // ---- phase A: fusion (wave per row, 8 rows/wave) ----
    for (int rr = wv; rr < 32; rr += 4) {
        int bl = bm0 + rr;
        int b = bl / ELEN;
        int u = map[eid[bl]];
        const u16* kg = KGU + (size_t)u * HDIM;
        const u16* im = IMU + (size_t)u * HDIM;
        const u16* tx = TXU + (size_t)u * HDIM;
        const float* qkg = qp + (size_t)b * 1536;
        const float* qim = qkg + 512;
        const float* qtx = qkg + 1024;
        float pkg = 0.f, pim = 0.f, ptx = 0.f;
        for (int e = lane; e < HDIM; e += 64) {
            pkg += bf2f(kg[e]) * qkg[e];
            pim += bf2f(im[e]) * qim[e];
            ptx += bf2f(tx[e]) * qtx[e];
        }
        #pragma unroll
        for (int off = 32; off; off >>= 1) {
            pkg += __shfl_down(pkg, off);
            pim += __shfl_down(pim, off);
            ptx += __shfl_down(ptx, off);
        }
        float w0, w1, w2;
        if (lane == 0) {
            float a = pkg + ct[0 * BATCH + b];
            float c1 = pim + ct[1 * BATCH + b];
            float c2 = ptx + ct[2 * BATCH + b];
            float mx = fmaxf(a, fmaxf(c1, c2));
            float ea = __expf(a - mx), eb = __expf(c1 - mx), ec = __expf(c2 - mx);
            float inv = 1.f / (ea + eb + ec);
            w0 = ea * inv; w1 = eb * inv; w2 = ec * inv;
        }
        w0 = __shfl(w0, 0); w1 = __shfl(w1, 0); w2 = __shfl(w2, 0);
        for (int e = lane; e < HDIM; e += 64) {
            float v = w0 * bf2f(kg[e]) + w1 * bf2f(im[e]) + w2 * bf2f(tx[e]);
            FUS[rr][e] = f2bf(v);
        }
    }
    __syncthreads();

    // ---- phase B: P1[32][256] = relu(FUS @ W1T^T + b1); wave wv covers cols wv*64..+64
    {
        const int rl = lane & 15;
        const int kgrp = lane >> 4;
        f32x4 acc[2][4];
        #pragma unroll
        for (int i = 0; i < 2; ++i)
            #pragma unroll
            for (int j = 0; j < 4; ++j)
                #pragma unroll
                for (int r = 0; r < 4; ++r) acc[i][j][r] = 0.f;
        for (int kk = 0; kk < 512; kk += 32) {
            int k8 = kk + kgrp * 8;
            bf16x8 af[2], bf[4];
            #pragma unroll
            for (int i = 0; i < 2; ++i) af[i] = *(const bf16x8*)&FUS[i * 16 + rl][k8];
            #pragma unroll
            for (int j = 0; j < 4; ++j) {
                int n = wv * 64 + j * 16 + rl;
                bf[j] = *(const bf16x8*)&W1T[(size_t)n * 512 + k8];
            }
            #pragma unroll
            for (int i = 0; i < 2; ++i)
                #pragma unroll
                for (int j = 0; j < 4; ++j)
                    acc[i][j] = __builtin_amdgcn_mfma_f32_16x16x32_bf16(af[i], bf[j], acc[i][j], 0, 0, 0);
        }
        const int rg = lane >> 4;
        #pragma unroll
        for (int i = 0; i < 2; ++i)
            #pragma unroll
            for (int j = 0; j < 4; ++j) {
                int col = wv * 64 + j * 16 + rl;
                float bv = pp1_b1[col];
                #pragma unroll
                for (int r = 0; r < 4; ++r) {
                    int row = i * 16 + rg * 4 + r;
                    P1s[row][col] = f2bf(fmaxf(acc[i][j][r] + bv, 0.f));
                }
            }
    }
    __syncthreads();

    // ---- phase C: H[32][512] = P1 @ W2T^T + b2 + FUS; wave covers cols wv*128..+128
    {
        const int rl = lane & 15;
        const int kgrp = lane >> 4;
        f32x4 acc[2][8];
        #pragma unroll
        for (int i = 0; i < 2; ++i)
            #pragma unroll
            for (int j = 0; j < 8; ++j)
                #pragma unroll
                for (int r = 0; r < 4; ++r) acc[i][j][r] = 0.f;
        for (int kk = 0; kk < 256; kk += 32) {
            int k8 = kk + kgrp * 8;
            bf16x8 af[2], bf[8];
            #pragma unroll
            for (int i = 0; i < 2; ++i) af[i] = *(const bf16x8*)&P1s[i * 16 + rl][k8];
            #pragma unroll
            for (int j = 0; j < 8; ++j) {
                int n = wv * 128 + j * 16 + rl;
                bf[j] = *(const bf16x8*)&W2T[(size_t)n * 256 + k8];
            }
            #pragma unroll
            for (int i = 0; i < 2; ++i)
                #pragma unroll
                for (int j = 0; j < 8; ++j)
                    acc[i][j] = __builtin_amdgcn_mfma_f32_16x16x32_bf16(af[i], bf[j], acc[i][j], 0, 0, 0);
        }
        const int rg = lane >> 4;
        #pragma unroll
        for (int i = 0; i < 2; ++i)
            #pragma unroll
            for (int j = 0; j < 8; ++j) {
                int col = wv * 128 + j * 16 + rl;
                float bv = pp1_b2[col];
                #pragma unroll
                for (int r = 0; r < 4; ++r) {
                    int row = i * 16 + rg * 4 + r;
                    float v = acc[i][j][r] + bv + bf2f(FUS[row][col]);
                    Hh[(size_t)(bm0 + row) * HDIM + col] = f2bf(v);
                }
            }
    }
}

// ---------------------------------------------------------------------------
extern "C" void kernel_launch(void* const* d_in, const int* in_sizes, int n_in,
                              void* d_out, int out_size, void* d_ws, size_t ws_size,
                              hipStream_t stream) {
    const int* entity_ids = (const int*)d_in[0];
    const float* token_embeds = (const float*)d_in[1];
    const int* edge_index = (const int*)d_in[2];
    const int* edge_type = (const int*)d_in[3];
    const float* node_embeds = (const float*)d_in[4];
    const float* rgcn_basis = (const float*)d_in[5];
    const float* rgcn_comp = (const float*)d_in[6];
    const float* rgcn_root = (const float*)d_in[7];
    const float* rgcn_bias = (const float*)d_in[8];
    const float* kg_proj_w = (const float*)d_in[9];
    const float* kg_proj_b = (const float*)d_in[10];
    const float* text_proj_w = (const float*)d_in[11];
    const float* text_proj_b = (const float*)d_in[12];
    const float* image_proj_w = (const float*)d_in[13];
    const float* image_proj_b = (const float*)d_in[14];
    const float* cq_w = (const float*)d_in[15];
    const float* cq_b = (const float*)d_in[16];
    const float* kgk_w = (const float*)d_in[17];
    const float* imk_w = (const float*)d_in[19];
    const float* txk_w = (const float*)d_in[21];
    const float* pp1_w1 = (const float*)d_in[23];
    const float* pp1_b1 = (const float*)d_in[24];
    const float* pp1_w2 = (const float*)d_in[25];
    const float* pp1_b2 = (const float*)d_in[26];
    const float* pp2_w = (const float*)d_in[27];
    const float* pp2_b = (const float*)d_in[28];
    const float* text_init = (const float*)d_in[29];
    const float* image_init = (const float*)d_in[30];

    const int E = in_sizes[3];  // 500000

    size_t off = 0;
    auto alloc = [&](size_t bytes) { size_t o = off; off += (bytes + 255) & ~(size_t)255; return o; };
    char* ws = (char*)d_ws;
    size_t map_o  = alloc((size_t)NENTS * 4);
    size_t nun_o  = alloc(4);
    size_t unq_o  = alloc((size_t)NPOS * 4);
    size_t cnt_o  = alloc((size_t)NPOS * NRELS * 4);
    size_t agg_o  = alloc((size_t)NPOS * NRELS * HALF * 4);   // 19.66MB; PP2T aliases after build_mbx
    size_t mbx_o  = alloc((size_t)NPOS * 2304 * 2);
    size_t bbt_o  = alloc((size_t)HALF * 2304 * 2);
    size_t rg_o   = alloc((size_t)NPOS * HALF * 2);
    size_t kgt_o  = alloc((size_t)HDIM * HALF * 2);
    size_t kgu_o  = alloc((size_t)NPOS * HDIM * 2);
    size_t txin_o = alloc((size_t)NPOS * TXTD * 2);
    size_t imin_o = alloc((size_t)NPOS * TXTD * 2);
    size_t txt_o  = alloc((size_t)HDIM * TXTD * 2);
    size_t imt_o  = alloc((size_t)HDIM * TXTD * 2);
    size_t txu_o  = alloc((size_t)NPOS * HDIM * 2);
    size_t imu_o  = alloc((size_t)NPOS * HDIM * 2);
    size_t qb_o   = alloc((size_t)BATCH * HDIM * 2);
    size_t kgw_o  = alloc((size_t)3 * HDIM * HDIM * 2);
    size_t qp_o   = alloc((size_t)BATCH * 3 * HDIM * 4);
    size_t ct_o   = alloc((size_t)3 * BATCH * 4);
    size_t zb_o   = alloc((size_t)1536 * 4);
    size_t w1t_o  = alloc((size_t)HALF * HDIM * 2);
    size_t w2t_o  = alloc((size_t)HDIM * HALF * 2);
    size_t h_o    = alloc((size_t)NPOS * HDIM * 2);
    if (off > ws_size) return;

    int* map = (int*)(ws + map_o);
    int* nuniq = (int*)(ws + nun_o);
    int* uniq = (int*)(ws + unq_o);
    float* cnt = (float*)(ws + cnt_o);
    float* agg = (float*)(ws + agg_o);
    u16* MBX = (u16*)(ws + mbx_o);
    u16* BBT = (u16*)(ws + bbt_o);
    u16* RG  = (u16*)(ws + rg_o);
    u16* KGT = (u16*)(ws + kgt_o);
    u16* KGU = (u16*)(ws + kgu_o);
    u16* TXIN = (u16*)(ws + txin_o);
    u16* IMIN = (u16*)(ws + imin_o);
    u16* TXT = (u16*)(ws + txt_o);
    u16* IMT = (u16*)(ws + imt_o);
    u16* TXU = (u16*)(ws + txu_o);
    u16* IMU = (u16*)(ws + imu_o);
    u16* QB  = (u16*)(ws + qb_o);
    u16* KGW = (u16*)(ws + kgw_o);
    float* QP  = (float*)(ws + qp_o);
    float* CT  = (float*)(ws + ct_o);
    float* ZB  = (float*)(ws + zb_o);
    u16* W1T = (u16*)(ws + w1t_o);
    u16* W2T = (u16*)(ws + w2t_o);
    u16* Hh  = (u16*)(ws + h_o);
    u16* PP2T = (u16*)(ws + agg_o);  // alias: agg dead after build_mbx
    float* OUT = (float*)d_out;

    // 1) init
    init_kernel<<<1024, 256, 0, stream>>>(agg, cnt, map, nuniq, ZB, OUT + (out_size - 1));
    // 2) dedup
    dedup_kernel<<<(NPOS + 255) / 256, 256, 0, stream>>>(entity_ids, map, uniq, nuniq);
    // 3) mid: qct | gather | edge
    mid_kernel<<<1024, 256, 0, stream>>>(
        token_embeds, cq_w, cq_b, (const float*)d_in[18], (const float*)d_in[20],
        (const float*)d_in[22], QB, CT,
        uniq, nuniq, text_init, image_init, TXIN, IMIN,
        edge_index, edge_type, map, node_embeds, agg, cnt, E);
    // 4) build MBX
    build_mbx_kernel<<<NPOS, 256, 0, stream>>>(agg, cnt, uniq, nuniq, rgcn_comp, node_embeds, MBX);
    // 5) weight prep (PP2T overwrites agg — after build_mbx)
    PrepArgs pa;
    pa.src[0] = rgcn_basis;  pa.dst[0] = BBT;
    pa.src[1] = rgcn_root;   pa.dst[1] = BBT;
    pa.src[2] = kg_proj_w;   pa.dst[2] = KGT;
    pa.src[3] = text_proj_w; pa.dst[3] = TXT;
    pa.src[4] = image_proj_w; pa.dst[4] = IMT;
    pa.src[5] = pp1_w1;      pa.dst[5] = W1T;
    pa.src[6] = pp1_w2;      pa.dst[6] = W2T;
    pa.src[7] = pp2_w;       pa.dst[7] = PP2T;
    pa.src[8] = kgk_w;       pa.dst[8] = KGW;
    pa.src[9] = imk_w;       pa.dst[9] = KGW + (size_t)HDIM * HDIM;
    pa.src[10] = txk_w;      pa.dst[10] = KGW + (size_t)2 * HDIM * HDIM;
    prep_kernel<<<8640, 256, 0, stream>>>(pa);
    // 6) QP + RG hetero
    gemmA_kernel<<<124, 256, 0, stream>>>(QB, KGW, ZB, QP, MBX, BBT, rgcn_bias, RG);
    // 7) KGU / TXU / IMU batched
    Proj3Args p3;
    p3.A[0] = RG;   p3.B[0] = KGT; p3.bias[0] = kg_proj_b;    p3.C[0] = KGU; p3.K[0] = HALF;
    p3.A[1] = TXIN; p3.B[1] = TXT; p3.bias[1] = text_proj_b;  p3.C[1] = TXU; p3.K[1] = TXTD;
    p3.A[2] = IMIN; p3.B[2] = IMT; p3.bias[2] = image_proj_b; p3.C[2] = IMU; p3.K[2] = TXTD;
    proj3_kernel<<<dim3(HDIM / 64, NPOS / 64, 3), 256, 0, stream>>>(p3);
    // 8) tail: fusion + P1 + H
    tail_kernel<<<NPOS / 32, 256, 0, stream>>>(entity_ids, map, KGU, IMU, TXU, QP, CT,
                                               W1T, pp1_b1, W2T, pp1_b2, Hh);
    // 9) OUT = scatter(H @ pp2_w + pp2_b)
    mfma_gemm<128, 128, 64, 64, 0, false, true, false><<<dim3(12288 / 128, (NPOS + 127) / 128), 256, 0, stream>>>(
        Hh, PP2T, pp2_b, nullptr, OUT, NPOS, 12288, HDIM);
}

// Round 5
// 187.907 us; speedup vs baseline: 1.3811x; 1.3811x over previous
//
#include <hip/hip_runtime.h>

#define HDIM 512
#define HALF 256
#define NRELS 12
#define NBASES 8
#define NLAYERS 12
#define NBLOCKS 2
#define NHEADS 8
#define NENTS 50000
#define TXTD 768
#define BATCH 32
#define ELEN 50
#define SLEN 128
#define NPOS (BATCH * ELEN)   // 1600
#define NSEG (NPOS * NRELS)   // 19200
#define BCAP 64               // per-(node,rel) bucket capacity; Poisson(0.83) => P(>64) ~ 0

typedef unsigned short u16;
typedef __attribute__((ext_vector_type(8))) __bf16 bf16x8;
typedef __attribute__((ext_vector_type(4))) float f32x4;

__device__ __forceinline__ u16 f2bf(float f) {
    unsigned int u = __float_as_uint(f);
    unsigned int r = (u + 0x7FFFu + ((u >> 16) & 1u)) >> 16;
    return (u16)r;
}
__device__ __forceinline__ float bf2f(u16 v) {
    return __uint_as_float(((unsigned int)v) << 16);
}

#define ASYNC_COPY16(g, l)                                                              \
    __builtin_amdgcn_global_load_lds((const __attribute__((address_space(1))) void*)(g), \
                                     (__attribute__((address_space(3))) unsigned int*)(l), 16, 0, 0)

// ---------------------------------------------------------------------------
// 0) init: map=-1, segcnt=0, ZB=0, nuniq/loss=0, SW bias rows (1536..1538)
// ---------------------------------------------------------------------------
__global__ void init_kernel(int* __restrict__ map, int* __restrict__ segcnt,
                            int* __restrict__ nuniq, float* __restrict__ zb,
                            const float* __restrict__ kgb, const float* __restrict__ imb,
                            const float* __restrict__ txb, u16* __restrict__ SW,
                            float* __restrict__ out_last) {
    int tid = blockIdx.x * blockDim.x + threadIdx.x;
    int nt = gridDim.x * blockDim.x;
    int4 m4 = {-1, -1, -1, -1};
    for (int i = tid; i < NENTS / 4; i += nt) ((int4*)map)[i] = m4;
    int4 z4 = {0, 0, 0, 0};
    for (int i = tid; i < NSEG / 4; i += nt) ((int4*)segcnt)[i] = z4;
    for (int i = tid; i < 1600; i += nt) zb[i] = 0.f;
    if (tid < HDIM) {
        SW[(size_t)1536 * HDIM + tid] = f2bf(kgb[tid]);
        SW[(size_t)1537 * HDIM + tid] = f2bf(imb[tid]);
        SW[(size_t)1538 * HDIM + tid] = f2bf(txb[tid]);
    }
    if (tid == 0) { *nuniq = 0; *out_last = 0.f; }
}

// ---------------------------------------------------------------------------
// 1) Dedupe entity ids
// ---------------------------------------------------------------------------
__global__ void dedup_kernel(const int* __restrict__ eid, int* __restrict__ map,
                             int* __restrict__ uniq, int* __restrict__ nuniq) {
    int i = blockIdx.x * blockDim.x + threadIdx.x;
    if (i >= NPOS) return;
    int n = eid[i];
    int old = atomicCAS(&map[n], -1, -2);
    if (old == -1) {
        int idx = atomicAdd(nuniq, 1);
        uniq[idx] = n;
        __threadfence();
        map[n] = idx;
    }
}

// ---------------------------------------------------------------------------
// 2) mid: {tokmean(64) | gather_txim(288) | edge filter E1(672)} — independent
// ---------------------------------------------------------------------------
__global__ __launch_bounds__(256) void mid_kernel(
    const float* __restrict__ tok, u16* __restrict__ TMEAN,
    const int* __restrict__ uniq, const int* __restrict__ nuniq,
    const float* __restrict__ txi, const float* __restrict__ imi,
    u16* __restrict__ TXIN, u16* __restrict__ IMIN,
    const int* __restrict__ ei, const int* __restrict__ et, const int* __restrict__ map,
    int* __restrict__ segcnt, int* __restrict__ bucket, int E) {
    int blk = blockIdx.x;
    int t = threadIdx.x;
    if (blk < 64) {
        // tokmean[b][col] = mean over SLEN
        int b = blk >> 1;
        int col = (blk & 1) * 256 + t;
        float s = 0.f;
        for (int si = 0; si < SLEN; ++si) s += tok[((size_t)b * SLEN + si) * HDIM + col];
        TMEAN[(size_t)b * HDIM + col] = f2bf(s * (1.0f / SLEN));
    } else if (blk < 352) {
        // gather text/image rows (288 blocks)
        if (t >= TXTD / 4) return;
        int nu = *nuniq;
        for (int u = blk - 64; u < NPOS; u += 288) {
            if (u >= nu) {
                ushort4 z = {0, 0, 0, 0};
                ((ushort4*)(TXIN + (size_t)u * TXTD))[t] = z;
                ((ushort4*)(IMIN + (size_t)u * TXTD))[t] = z;
                continue;
            }
            int n = uniq[u];
            float4 v = ((const float4*)(txi + (size_t)n * TXTD))[t];
            ushort4 o;
            o.x = f2bf(v.x); o.y = f2bf(v.y); o.z = f2bf(v.z); o.w = f2bf(v.w);
            ((ushort4*)(TXIN + (size_t)u * TXTD))[t] = o;
            v = ((const float4*)(imi + (size_t)n * TXTD))[t];
            o.x = f2bf(v.x); o.y = f2bf(v.y); o.z = f2bf(v.z); o.w = f2bf(v.w);
            ((ushort4*)(IMIN + (size_t)u * TXTD))[t] = o;
        }
    } else {
        // E1: filter edges into per-(node,rel) buckets. ~15.7K tiny atomics total.
        const int* __restrict__ dstA = ei + E;
        int tid0 = (blk - 352) * 256 + t;
        const int stride = 672 * 256;
        for (int e = tid0; e < E; e += stride) {
            int c = map[dstA[e]];
            if (c >= 0) {
                int seg = c * NRELS + et[e];
                int p = atomicAdd(&segcnt[seg], 1);
                if (p < BCAP) bucket[seg * BCAP + p] = ei[e];
            }
        }
    }
}

// ---------------------------------------------------------------------------
// 3) ONE weight-prep kernel: 9 transposes + 3 converts
// ---------------------------------------------------------------------------
struct PrepArgs {
    const float* src[12];
    u16* dst[12];
};
__global__ __launch_bounds__(256) void prep_kernel(PrepArgs a) {
    // 0:basis 1:root 2:kgproj 3:txproj 4:improj 5:w1 6:w2 7:pp2 8:cq | 9,10,11: score convs
    constexpr int NN[9]   = {256, 256, 512, 512, 512, 256, 512, 12288, 512};
    constexpr int LDT[9]  = {2304, 2304, 256, 768, 768, 512, 256, 512, 512};
    constexpr int KOFF[9] = {0, 2048, 0, 0, 0, 0, 0, 0, 0};
    constexpr int BASE[13] = {0, 512, 576, 704, 1088, 1472, 1600, 1728, 7872, 8128, 8384, 8640, 8896};
    __shared__ u16 tb[32][33];
    int bid = blockIdx.x;
    int op = 0;
    #pragma unroll
    for (int i = 1; i < 12; ++i)
        if (bid >= BASE[i]) op = i;
    int idx = bid - BASE[op];
    if (op < 9) {
        int Nv = 0, ldt = 0, koff = 0;
        #pragma unroll
        for (int i = 0; i < 9; ++i)
            if (op == i) { Nv = NN[i]; ldt = LDT[i]; koff = KOFF[i]; }
        int ncols = Nv / 32;
        int n0 = (idx % ncols) * 32, k0 = (idx / ncols) * 32;
        const float* W = a.src[op];
        u16* WT = a.dst[op];
        int tx = threadIdx.x & 31, ty = threadIdx.x >> 5;
        #pragma unroll
        for (int i = ty; i < 32; i += 8)
            tb[i][tx] = f2bf(W[(size_t)(k0 + i) * Nv + n0 + tx]);
        __syncthreads();
        #pragma unroll
        for (int i = ty; i < 32; i += 8)
            WT[(size_t)(n0 + i) * ldt + koff + k0 + tx] = tb[tx][i];
    } else {
        int e = idx * 1024 + threadIdx.x * 4;
        float4 v = *(const float4*)(a.src[op] + e);
        ushort4 o;
        o.x = f2bf(v.x); o.y = f2bf(v.y); o.z = f2bf(v.z); o.w = f2bf(v.w);
        *(ushort4*)(a.dst[op] + e) = o;
    }
}

// ---------------------------------------------------------------------------
// MFMA bf16 GEMM body
// ---------------------------------------------------------------------------
template <int BM, int BN, int WM, int WN, int ACT, bool RES, bool SCATTER, bool OUTBF>
__device__ __forceinline__ void gemm_body(const u16* __restrict__ A, const u16* __restrict__ BT,
                                          const float* __restrict__ bias, const float* __restrict__ res,
                                          void* __restrict__ Cout, int M, int N, int K,
                                          int bx, int by) {
    constexpr int MF = WM / 16, NF = WN / 16;
    constexpr int NWC = BN / WN;
    __shared__ u16 ldsA[BM][64];
    __shared__ u16 ldsB[BN][64];
    const int tid = threadIdx.x;
    const int lane = tid & 63;
    const int wv = tid >> 6;
    const int m0 = by * BM;
    const int n0 = bx * BN;
    const int wr = wv / NWC, wc = wv % NWC;
    const int srow = lane >> 3;
    const int sslot = lane & 7;

    f32x4 acc[MF][NF];
    #pragma unroll
    for (int i = 0; i < MF; ++i)
        #pragma unroll
        for (int j = 0; j < NF; ++j)
            #pragma unroll
            for (int r = 0; r < 4; ++r) acc[i][j][r] = 0.f;

    for (int k0 = 0; k0 < K; k0 += 64) {
        #pragma unroll
        for (int i = 0; i < BM / 32; ++i) {
            int R = wv * (BM / 4) + i * 8 + srow;
            int gm = m0 + R;
            gm = gm < M ? gm : M - 1;
            int s = sslot ^ (R & 7);
            ASYNC_COPY16(A + (size_t)gm * K + k0 + s * 8, &ldsA[wv * (BM / 4) + i * 8][0]);
        }
        #pragma unroll
        for (int i = 0; i < BN / 32; ++i) {
            int R = wv * (BN / 4) + i * 8 + srow;
            int s = sslot ^ (R & 7);
            ASYNC_COPY16(BT + (size_t)(n0 + R) * K + k0 + s * 8, &ldsB[wv * (BN / 4) + i * 8][0]);
        }
        __syncthreads();
        #pragma unroll
        for (int ks = 0; ks < 2; ++ks) {
            bf16x8 af[MF], bf[NF];
            int kg = ks * 4 + (lane >> 4);
            int rl = lane & 15;
            #pragma unroll
            for (int i = 0; i < MF; ++i) {
                int row = wr * WM + i * 16 + rl;
                af[i] = *(const bf16x8*)&ldsA[row][(kg ^ (row & 7)) * 8];
            }
            #pragma unroll
            for (int j = 0; j < NF; ++j) {
                int row = wc * WN + j * 16 + rl;
                bf[j] = *(const bf16x8*)&ldsB[row][(kg ^ (row & 7)) * 8];
            }
            #pragma unroll
            for (int i = 0; i < MF; ++i)
                #pragma unroll
                for (int j = 0; j < NF; ++j)
                    acc[i][j] = __builtin_amdgcn_mfma_f32_16x16x32_bf16(af[i], bf[j], acc[i][j], 0, 0, 0);
        }
        __syncthreads();
    }

    const int rl = lane & 15, rg = lane >> 4;
    #pragma unroll
    for (int i = 0; i < MF; ++i) {
        #pragma unroll
        for (int j = 0; j < NF; ++j) {
            int col = n0 + wc * WN + j * 16 + rl;
            float bv = bias[col];
            #pragma unroll
            for (int r = 0; r < 4; ++r) {
                int row = m0 + wr * WM + i * 16 + rg * 4 + r;
                if (row >= M) continue;
                float x = acc[i][j][r] + bv;
                if (ACT == 1) x = fmaxf(x, 0.f);
                if (RES) x += res[(size_t)row * N + col];
                if (SCATTER) {
                    int layer = col >> 10, blk = (col >> 9) & 1, head = (col >> 6) & 7, hd = col & 63;
                    int bb = row / ELEN, ll = row - bb * ELEN;
                    size_t oi = (((((size_t)layer * NBLOCKS + blk) * BATCH + bb) * NHEADS + head) * ELEN + ll) * 64 + hd;
                    ((float*)Cout)[oi] = x;
                } else if (OUTBF) {
                    ((u16*)Cout)[(size_t)row * N + col] = f2bf(x);
                } else {
                    ((float*)Cout)[(size_t)row * N + col] = x;
                }
            }
        }
    }
}

template <int BM, int BN, int WM, int WN, int ACT, bool RES, bool SCATTER, bool OUTBF>
__global__ __launch_bounds__(256)
void mfma_gemm(const u16* __restrict__ A, const u16* __restrict__ BT,
               const float* __restrict__ bias, const float* __restrict__ res,
               void* __restrict__ Cout, int M, int N, int K) {
    gemm_body<BM, BN, WM, WN, ACT, RES, SCATTER, OUTBF>(A, BT, bias, res, Cout, M, N, K,
                                                        blockIdx.x, blockIdx.y);
}

// ---------------------------------------------------------------------------
// 4) build: blocks 0..1599 = MBX gather-sum (atomic-free); 1600..1607 = QB GEMM
// ---------------------------------------------------------------------------
__global__ __launch_bounds__(256) void build_kernel(
    const int* __restrict__ segcnt, const int* __restrict__ bucket,
    const int* __restrict__ uniq, const int* __restrict__ nuniq,
    const float* __restrict__ comp, const float* __restrict__ x, u16* __restrict__ MBX,
    const u16* __restrict__ TMEAN, const u16* __restrict__ CQT,
    const float* __restrict__ cq_b, u16* __restrict__ QB) {
    int blk = blockIdx.x;
    if (blk >= NPOS) {
        // QB[32][512] = TMEAN @ CQT^T + cq_b   (bf16 out)
        gemm_body<64, 64, 32, 32, 0, false, false, true>(TMEAN, CQT, cq_b, nullptr, QB,
                                                         BATCH, HDIM, HDIM, blk - NPOS, 0);
        return;
    }
    int u = blk;
    int i = threadIdx.x;  // 256
    __shared__ float sc[NRELS * NBASES];
    if (i < NRELS * NBASES) sc[i] = comp[i];
    __syncthreads();
    u16* row = MBX + (size_t)u * 2304;
    int nu = *nuniq;
    if (u >= nu) {
        for (int b = 0; b < NBASES + 1; ++b) row[b * HALF + i] = 0;
        return;
    }
    float mr[NRELS];
    #pragma unroll
    for (int r = 0; r < NRELS; ++r) {
        int seg = u * NRELS + r;
        int c = segcnt[seg];
        int n = min(c, BCAP);
        float acc = 0.f;
        for (int e = 0; e < n; ++e) {
            int s = bucket[seg * BCAP + e];
            acc += x[(size_t)s * HALF + i];
        }
        mr[r] = acc * (1.f / fmaxf((float)c, 1.f));
    }
    #pragma unroll
    for (int b = 0; b < NBASES; ++b) {
        float a = 0.f;
        #pragma unroll
        for (int r = 0; r < NRELS; ++r) a += sc[r * NBASES + b] * mr[r];
        row[b * HALF + i] = f2bf(a);
    }
    row[NBASES * HALF + i] = f2bf(x[(size_t)uniq[u] * HALF + i]);
}

// ---------------------------------------------------------------------------
// 5) hetero {QP (25 tiles, N=1600 incl. ct cols) + RG (100 tiles)}
// ---------------------------------------------------------------------------
__global__ __launch_bounds__(256) void gemmA_kernel(
    const u16* __restrict__ QB, const u16* __restrict__ SW, const float* __restrict__ ZB,
    float* __restrict__ QP, const u16* __restrict__ MBX, const u16* __restrict__ BBT,
    const float* __restrict__ rgcn_bias, u16* __restrict__ RG) {
    if (blockIdx.x < 25) {
        gemm_body<64, 64, 32, 32, 0, false, false, false>(QB, SW, ZB, nullptr, QP,
                                                          BATCH, 1600, HDIM, blockIdx.x, 0);
    } else {
        int idx = blockIdx.x - 25;
        gemm_body<64, 64, 32, 32, 0, false, false, true>(MBX, BBT, rgcn_bias, nullptr, RG,
                                                         NPOS, HALF, 2304, idx % 4, idx / 4);
    }
}

// 6) batched 3-way projection
struct Proj3Args {
    const u16* A[3];
    const u16* B[3];
    const float* bias[3];
    u16* C[3];
    int K[3];
};
__global__ __launch_bounds__(256) void proj3_kernel(Proj3Args a) {
    int z = blockIdx.z;
    gemm_body<64, 64, 32, 32, 0, false, false, true>(a.A[z], a.B[z], a.bias[z], nullptr,
                                                     a.C[z], NPOS, HDIM, a.K[z],
                                                     blockIdx.x, blockIdx.y);
}

// ---------------------------------------------------------------------------
// 7) tail: fusion + P1 + H fused. 32 rows/block, 50 blocks, 4 waves.
//    qp stride 1600; ct = qp cols 1536..1538.
// ---------------------------------------------------------------------------
__global__ __launch_bounds__(256) void tail_kernel(
    const int* __restrict__ eid, const int* __restrict__ map,
    const u16* __restrict__ KGU, const u16* __restrict__ IMU, const u16* __restrict__ TXU,
    const float* __restrict__ qp,
    const u16* __restrict__ W1T, const float* __restrict__ pp1_b1,
    const u16* __restrict__ W2T, const float* __restrict__ pp1_b2,
    u16* __restrict__ Hh) {
    __shared__ u16 FUS[32][520];
    __shared__ u16 P1s[32][264];
    const int bm0 = blockIdx.x * 32;
    const int lane = threadIdx.x & 63;
    const int wv = threadIdx.x >> 6;

    // ---- phase A: fusion ----
    for (int rr = wv; rr < 32; rr += 4) {
        int bl = bm0 + rr;
        int b = bl / ELEN;
        int u = map[eid[bl]];
        const u16* kg = KGU + (size_t)u * HDIM;
        const u16* im = IMU + (size_t)u * HDIM;
        const u16* tx = TXU + (size_t)u * HDIM;
        const float* qrow = qp + (size_t)b * 1600;
        float pkg = 0.f, pim = 0.f, ptx = 0.f;
        for (int e = lane; e < HDIM; e += 64) {
            pkg += bf2f(kg[e]) * qrow[e];
            pim += bf2f(im[e]) * qrow[512 + e];
            ptx += bf2f(tx[e]) * qrow[1024 + e];
        }
        #pragma unroll
        for (int off = 32; off; off >>= 1) {
            pkg += __shfl_down(pkg, off);
            pim += __shfl_down(pim, off);
            ptx += __shfl_down(ptx, off);
        }
        float w0, w1, w2;
        if (lane == 0) {
            float a = pkg + qrow[1536];
            float c1 = pim + qrow[1537];
            float c2 = ptx + qrow[1538];
            float mx = fmaxf(a, fmaxf(c1, c2));
            float ea = __expf(a - mx), eb = __expf(c1 - mx), ec = __expf(c2 - mx);
            float inv = 1.f / (ea + eb + ec);
            w0 = ea * inv; w1 = eb * inv; w2 = ec * inv;
        }
        w0 = __shfl(w0, 0); w1 = __shfl(w1, 0); w2 = __shfl(w2, 0);
        for (int e = lane; e < HDIM; e += 64) {
            float v = w0 * bf2f(kg[e]) + w1 * bf2f(im[e]) + w2 * bf2f(tx[e]);
            FUS[rr][e] = f2bf(v);
        }
    }
    __syncthreads();

    // ---- phase B: P1 = relu(FUS @ W1T^T + b1) ----
    {
        const int rl = lane & 15;
        const int kgrp = lane >> 4;
        f32x4 acc[2][4];
        #pragma unroll
        for (int i = 0; i < 2; ++i)
            #pragma unroll
            for (int j = 0; j < 4; ++j)
                #pragma unroll
                for (int r = 0; r < 4; ++r) acc[i][j][r] = 0.f;
        for (int kk = 0; kk < 512; kk += 32) {
            int k8 = kk + kgrp * 8;
            bf16x8 af[2], bf[4];
            #pragma unroll
            for (int i = 0; i < 2; ++i) af[i] = *(const bf16x8*)&FUS[i * 16 + rl][k8];
            #pragma unroll
            for (int j = 0; j < 4; ++j) {
                int n = wv * 64 + j * 16 + rl;
                bf[j] = *(const bf16x8*)&W1T[(size_t)n * 512 + k8];
            }
            #pragma unroll
            for (int i = 0; i < 2; ++i)
                #pragma unroll
                for (int j = 0; j < 4; ++j)
                    acc[i][j] = __builtin_amdgcn_mfma_f32_16x16x32_bf16(af[i], bf[j], acc[i][j], 0, 0, 0);
        }
        const int rg = lane >> 4;
        #pragma unroll
        for (int i = 0; i < 2; ++i)
            #pragma unroll
            for (int j = 0; j < 4; ++j) {
                int col = wv * 64 + j * 16 + rl;
                float bv = pp1_b1[col];
                #pragma unroll
                for (int r = 0; r < 4; ++r) {
                    int row = i * 16 + rg * 4 + r;
                    P1s[row][col] = f2bf(fmaxf(acc[i][j][r] + bv, 0.f));
                }
            }
    }
    __syncthreads();

    // ---- phase C: H = P1 @ W2T^T + b2 + FUS ----
    {
        const int rl = lane & 15;
        const int kgrp = lane >> 4;
        f32x4 acc[2][8];
        #pragma unroll
        for (int i = 0; i < 2; ++i)
            #pragma unroll
            for (int j = 0; j < 8; ++j)
                #pragma unroll
                for (int r = 0; r < 4; ++r) acc[i][j][r] = 0.f;
        for (int kk = 0; kk < 256; kk += 32) {
            int k8 = kk + kgrp * 8;
            bf16x8 af[2], bf[8];
            #pragma unroll
            for (int i = 0; i < 2; ++i) af[i] = *(const bf16x8*)&P1s[i * 16 + rl][k8];
            #pragma unroll
            for (int j = 0; j < 8; ++j) {
                int n = wv * 128 + j * 16 + rl;
                bf[j] = *(const bf16x8*)&W2T[(size_t)n * 256 + k8];
            }
            #pragma unroll
            for (int i = 0; i < 2; ++i)
                #pragma unroll
                for (int j = 0; j < 8; ++j)
                    acc[i][j] = __builtin_amdgcn_mfma_f32_16x16x32_bf16(af[i], bf[j], acc[i][j], 0, 0, 0);
        }
        const int rg = lane >> 4;
        #pragma unroll
        for (int i = 0; i < 2; ++i)
            #pragma unroll
            for (int j = 0; j < 8; ++j) {
                int col = wv * 128 + j * 16 + rl;
                float bv = pp1_b2[col];
                #pragma unroll
                for (int r = 0; r < 4; ++r) {
                    int row = i * 16 + rg * 4 + r;
                    float v = acc[i][j][r] + bv + bf2f(FUS[row][col]);
                    Hh[(size_t)(bm0 + row) * HDIM + col] = f2bf(v);
                }
            }
    }
}

// ---------------------------------------------------------------------------
extern "C" void kernel_launch(void* const* d_in, const int* in_sizes, int n_in,
                              void* d_out, int out_size, void* d_ws, size_t ws_size,
                              hipStream_t stream) {
    const int* entity_ids = (const int*)d_in[0];
    const float* token_embeds = (const float*)d_in[1];
    const int* edge_index = (const int*)d_in[2];
    const int* edge_type = (const int*)d_in[3];
    const float* node_embeds = (const float*)d_in[4];
    const float* rgcn_basis = (const float*)d_in[5];
    const float* rgcn_comp = (const float*)d_in[6];
    const float* rgcn_root = (const float*)d_in[7];
    const float* rgcn_bias = (const float*)d_in[8];
    const float* kg_proj_w = (const float*)d_in[9];
    const float* kg_proj_b = (const float*)d_in[10];
    const float* text_proj_w = (const float*)d_in[11];
    const float* text_proj_b = (const float*)d_in[12];
    const float* image_proj_w = (const float*)d_in[13];
    const float* image_proj_b = (const float*)d_in[14];
    const float* cq_w = (const float*)d_in[15];
    const float* cq_b = (const float*)d_in[16];
    const float* kgk_w = (const float*)d_in[17];
    const float* imk_w = (const float*)d_in[19];
    const float* txk_w = (const float*)d_in[21];
    const float* pp1_w1 = (const float*)d_in[23];
    const float* pp1_b1 = (const float*)d_in[24];
    const float* pp1_w2 = (const float*)d_in[25];
    const float* pp1_b2 = (const float*)d_in[26];
    const float* pp2_w = (const float*)d_in[27];
    const float* pp2_b = (const float*)d_in[28];
    const float* text_init = (const float*)d_in[29];
    const float* image_init = (const float*)d_in[30];

    const int E = in_sizes[3];  // 500000

    size_t off = 0;
    auto alloc = [&](size_t bytes) { size_t o = off; off += (bytes + 255) & ~(size_t)255; return o; };
    char* ws = (char*)d_ws;
    size_t map_o  = alloc((size_t)NENTS * 4);
    size_t nun_o  = alloc(4);
    size_t unq_o  = alloc((size_t)NPOS * 4);
    size_t scnt_o = alloc((size_t)NSEG * 4);
    size_t bkt_o  = alloc((size_t)NSEG * BCAP * 4);           // 4.9MB
    size_t mbx_o  = alloc((size_t)NPOS * 2304 * 2);
    size_t bbt_o  = alloc((size_t)HALF * 2304 * 2);
    size_t rg_o   = alloc((size_t)NPOS * HALF * 2);
    size_t kgt_o  = alloc((size_t)HDIM * HALF * 2);
    size_t kgu_o  = alloc((size_t)NPOS * HDIM * 2);
    size_t txin_o = alloc((size_t)NPOS * TXTD * 2);
    size_t imin_o = alloc((size_t)NPOS * TXTD * 2);
    size_t txt_o  = alloc((size_t)HDIM * TXTD * 2);
    size_t imt_o  = alloc((size_t)HDIM * TXTD * 2);
    size_t txu_o  = alloc((size_t)NPOS * HDIM * 2);
    size_t imu_o  = alloc((size_t)NPOS * HDIM * 2);
    size_t tm_o   = alloc((size_t)BATCH * HDIM * 2);
    size_t qb_o   = alloc((size_t)BATCH * HDIM * 2);
    size_t cqt_o  = alloc((size_t)HDIM * HDIM * 2);
    size_t sw_o   = alloc((size_t)1600 * HDIM * 2);           // kg/im/tx weights + 3 bias rows + pad
    size_t qp_o   = alloc((size_t)BATCH * 1600 * 4);
    size_t zb_o   = alloc((size_t)1600 * 4);
    size_t w1t_o  = alloc((size_t)HALF * HDIM * 2);
    size_t w2t_o  = alloc((size_t)HDIM * HALF * 2);
    size_t h_o    = alloc((size_t)NPOS * HDIM * 2);
    size_t pp2t_o = alloc((size_t)12288 * HDIM * 2);          // 12.6MB
    if (off > ws_size) return;

    int* map = (int*)(ws + map_o);
    int* nuniq = (int*)(ws + nun_o);
    int* uniq = (int*)(ws + unq_o);
    int* segcnt = (int*)(ws + scnt_o);
    int* bucket = (int*)(ws + bkt_o);
    u16* MBX = (u16*)(ws + mbx_o);
    u16* BBT = (u16*)(ws + bbt_o);
    u16* RG  = (u16*)(ws + rg_o);
    u16* KGT = (u16*)(ws + kgt_o);
    u16* KGU = (u16*)(ws + kgu_o);
    u16* TXIN = (u16*)(ws + txin_o);
    u16* IMIN = (u16*)(ws + imin_o);
    u16* TXT = (u16*)(ws + txt_o);
    u16* IMT = (u16*)(ws + imt_o);
    u16* TXU = (u16*)(ws + txu_o);
    u16* IMU = (u16*)(ws + imu_o);
    u16* TMEAN = (u16*)(ws + tm_o);
    u16* QB  = (u16*)(ws + qb_o);
    u16* CQT = (u16*)(ws + cqt_o);
    u16* SW  = (u16*)(ws + sw_o);
    float* QP  = (float*)(ws + qp_o);
    float* ZB  = (float*)(ws + zb_o);
    u16* W1T = (u16*)(ws + w1t_o);
    u16* W2T = (u16*)(ws + w2t_o);
    u16* Hh  = (u16*)(ws + h_o);
    u16* PP2T = (u16*)(ws + pp2t_o);
    float* OUT = (float*)d_out;

    // 1) init
    init_kernel<<<128, 256, 0, stream>>>(map, segcnt, nuniq, ZB,
                                         (const float*)d_in[18], (const float*)d_in[20],
                                         (const float*)d_in[22], SW, OUT + (out_size - 1));
    // 2) dedup
    dedup_kernel<<<(NPOS + 255) / 256, 256, 0, stream>>>(entity_ids, map, uniq, nuniq);
    // 3) mid: tokmean | gather | edge-filter
    mid_kernel<<<1024, 256, 0, stream>>>(token_embeds, TMEAN,
                                         uniq, nuniq, text_init, image_init, TXIN, IMIN,
                                         edge_index, edge_type, map, segcnt, bucket, E);
    // 4) weight prep
    PrepArgs pa;
    pa.src[0] = rgcn_basis;   pa.dst[0] = BBT;
    pa.src[1] = rgcn_root;    pa.dst[1] = BBT;
    pa.src[2] = kg_proj_w;    pa.dst[2] = KGT;
    pa.src[3] = text_proj_w;  pa.dst[3] = TXT;
    pa.src[4] = image_proj_w; pa.dst[4] = IMT;
    pa.src[5] = pp1_w1;       pa.dst[5] = W1T;
    pa.src[6] = pp1_w2;       pa.dst[6] = W2T;
    pa.src[7] = pp2_w;        pa.dst[7] = PP2T;
    pa.src[8] = cq_w;         pa.dst[8] = CQT;
    pa.src[9] = kgk_w;        pa.dst[9] = SW;
    pa.src[10] = imk_w;       pa.dst[10] = SW + (size_t)HDIM * HDIM;
    pa.src[11] = txk_w;       pa.dst[11] = SW + (size_t)2 * HDIM * HDIM;
    prep_kernel<<<8896, 256, 0, stream>>>(pa);
    // 5) build MBX (atomic-free gather-sum) + QB GEMM
    build_kernel<<<NPOS + 8, 256, 0, stream>>>(segcnt, bucket, uniq, nuniq, rgcn_comp,
                                               node_embeds, MBX, TMEAN, CQT, cq_b, QB);
    // 6) QP (incl. ct cols) + RG hetero
    gemmA_kernel<<<125, 256, 0, stream>>>(QB, SW, ZB, QP, MBX, BBT, rgcn_bias, RG);
    // 7) KGU / TXU / IMU batched
    Proj3Args p3;
    p3.A[0] = RG;   p3.B[0] = KGT; p3.bias[0] = kg_proj_b;    p3.C[0] = KGU; p3.K[0] = HALF;
    p3.A[1] = TXIN; p3.B[1] = TXT; p3.bias[1] = text_proj_b;  p3.C[1] = TXU; p3.K[1] = TXTD;
    p3.A[2] = IMIN; p3.B[2] = IMT; p3.bias[2] = image_proj_b; p3.C[2] = IMU; p3.K[2] = TXTD;
    proj3_kernel<<<dim3(HDIM / 64, NPOS / 64, 3), 256, 0, stream>>>(p3);
    // 8) tail: fusion + P1 + H
    tail_kernel<<<NPOS / 32, 256, 0, stream>>>(entity_ids, map, KGU, IMU, TXU, QP,
                                               W1T, pp1_b1, W2T, pp1_b2, Hh);
    // 9) OUT = scatter(H @ pp2_w + pp2_b)
    mfma_gemm<128, 128, 64, 64, 0, false, true, false><<<dim3(12288 / 128, (NPOS + 127) / 128), 256, 0, stream>>>(
        Hh, PP2T, pp2_b, nullptr, OUT, NPOS, 12288, HDIM);
}

// Round 6
// 153.913 us; speedup vs baseline: 1.6862x; 1.2209x over previous
//
#include <hip/hip_runtime.h>

#define HDIM 512
#define HALF 256
#define NRELS 12
#define NBASES 8
#define NLAYERS 12
#define NBLOCKS 2
#define NHEADS 8
#define NENTS 50000
#define TXTD 768
#define BATCH 32
#define ELEN 50
#define SLEN 128
#define NPOS (BATCH * ELEN)   // 1600
#define NSEG (NPOS * NRELS)   // 19200
#define BCAP 64

typedef unsigned short u16;
typedef __attribute__((ext_vector_type(8))) __bf16 bf16x8;
typedef __attribute__((ext_vector_type(4))) float f32x4;

__device__ __forceinline__ u16 f2bf(float f) {
    unsigned int u = __float_as_uint(f);
    unsigned int r = (u + 0x7FFFu + ((u >> 16) & 1u)) >> 16;
    return (u16)r;
}
__device__ __forceinline__ float bf2f(u16 v) {
    return __uint_as_float(((unsigned int)v) << 16);
}

#define ASYNC_COPY16(g, l)                                                              \
    __builtin_amdgcn_global_load_lds((const __attribute__((address_space(1))) void*)(g), \
                                     (__attribute__((address_space(3))) unsigned int*)(l), 16, 0, 0)

// ---------------------------------------------------------------------------
// 0) init: map=-1, segcnt=0, ZB=0, SW bias rows, biasC = rgcn_bias@kg_proj + kg_b
// ---------------------------------------------------------------------------
__global__ void init_kernel(int* __restrict__ map, int* __restrict__ segcnt,
                            int* __restrict__ nuniq, float* __restrict__ zb,
                            const float* __restrict__ kgb, const float* __restrict__ imb,
                            const float* __restrict__ txb, u16* __restrict__ SW,
                            const float* __restrict__ rgcn_bias,
                            const float* __restrict__ kg_proj_w,
                            const float* __restrict__ kg_proj_b,
                            float* __restrict__ biasC, float* __restrict__ out_last) {
    int blk = blockIdx.x;
    int t = threadIdx.x;
    if (blk >= 128) {
        // biasC[n] = sum_c rgcn_bias[c] * kg_proj_w[c][n] + kg_proj_b[n]
        int n = (blk - 128) * 256 + t;
        float acc = kg_proj_b[n];
        for (int c = 0; c < HALF; ++c) acc += rgcn_bias[c] * kg_proj_w[(size_t)c * HDIM + n];
        biasC[n] = acc;
        return;
    }
    int tid = blk * 256 + t;
    const int nt = 128 * 256;
    int4 m4 = {-1, -1, -1, -1};
    for (int i = tid; i < NENTS / 4; i += nt) ((int4*)map)[i] = m4;
    int4 z4 = {0, 0, 0, 0};
    for (int i = tid; i < NSEG / 4; i += nt) ((int4*)segcnt)[i] = z4;
    for (int i = tid; i < 2304; i += nt) zb[i] = 0.f;
    if (tid < HDIM) {
        SW[(size_t)1536 * HDIM + tid] = f2bf(kgb[tid]);
        SW[(size_t)1537 * HDIM + tid] = f2bf(imb[tid]);
        SW[(size_t)1538 * HDIM + tid] = f2bf(txb[tid]);
    }
    if (tid == 0) { *nuniq = 0; *out_last = 0.f; }
}

// ---------------------------------------------------------------------------
// 1) Dedupe entity ids
// ---------------------------------------------------------------------------
__global__ void dedup_kernel(const int* __restrict__ eid, int* __restrict__ map,
                             int* __restrict__ uniq, int* __restrict__ nuniq) {
    int i = blockIdx.x * blockDim.x + threadIdx.x;
    if (i >= NPOS) return;
    int n = eid[i];
    int old = atomicCAS(&map[n], -1, -2);
    if (old == -1) {
        int idx = atomicAdd(nuniq, 1);
        uniq[idx] = n;
        __threadfence();
        map[n] = idx;
    }
}

// ---------------------------------------------------------------------------
// 2) midprep: {tokmean(64) | gather(288) | edge-filter(672) | weight-prep(8896)}
// ---------------------------------------------------------------------------
struct PrepArgs {
    const float* src[12];
    u16* dst[12];
};

__global__ __launch_bounds__(256) void midprep_kernel(
    const float* __restrict__ tok, u16* __restrict__ TMEAN,
    const int* __restrict__ uniq, const int* __restrict__ nuniq,
    const float* __restrict__ txi, const float* __restrict__ imi,
    u16* __restrict__ TXIN, u16* __restrict__ IMIN,
    const int* __restrict__ ei, const int* __restrict__ et, const int* __restrict__ map,
    int* __restrict__ segcnt, int* __restrict__ bucket, int E, PrepArgs a) {
    int blk = blockIdx.x;
    int t = threadIdx.x;
    if (blk < 64) {
        // tokmean
        int b = blk >> 1;
        int col = (blk & 1) * 256 + t;
        float s = 0.f;
        for (int si = 0; si < SLEN; ++si) s += tok[((size_t)b * SLEN + si) * HDIM + col];
        TMEAN[(size_t)b * HDIM + col] = f2bf(s * (1.0f / SLEN));
    } else if (blk < 352) {
        // gather text/image rows
        if (t >= TXTD / 4) return;
        int nu = *nuniq;
        for (int u = blk - 64; u < NPOS; u += 288) {
            if (u >= nu) {
                ushort4 z = {0, 0, 0, 0};
                ((ushort4*)(TXIN + (size_t)u * TXTD))[t] = z;
                ((ushort4*)(IMIN + (size_t)u * TXTD))[t] = z;
                continue;
            }
            int n = uniq[u];
            float4 v = ((const float4*)(txi + (size_t)n * TXTD))[t];
            ushort4 o;
            o.x = f2bf(v.x); o.y = f2bf(v.y); o.z = f2bf(v.z); o.w = f2bf(v.w);
            ((ushort4*)(TXIN + (size_t)u * TXTD))[t] = o;
            v = ((const float4*)(imi + (size_t)n * TXTD))[t];
            o.x = f2bf(v.x); o.y = f2bf(v.y); o.z = f2bf(v.z); o.w = f2bf(v.w);
            ((ushort4*)(IMIN + (size_t)u * TXTD))[t] = o;
        }
    } else if (blk < 1024) {
        // edge filter into per-(node,rel) buckets
        const int* __restrict__ dstA = ei + E;
        int tid0 = (blk - 352) * 256 + t;
        const int stride = 672 * 256;
        for (int e = tid0; e < E; e += stride) {
            int c = map[dstA[e]];
            if (c >= 0) {
                int seg = c * NRELS + et[e];
                int p = atomicAdd(&segcnt[seg], 1);
                if (p < BCAP) bucket[seg * BCAP + p] = ei[e];
            }
        }
    } else {
        // weight prep: trans ops 0-6, conv ops 7-11
        constexpr int NN[7]  = {512, 512, 512, 256, 512, 12288, 512};
        constexpr int LDT[7] = {256, 768, 768, 512, 256, 512, 512};
        constexpr int BASE[13] = {0, 128, 512, 896, 1024, 1152, 7296,
                                  7552, 8064, 8128, 8384, 8640, 8896};
        __shared__ u16 tb[32][33];
        int bid = blk - 1024;
        int op = 0;
        #pragma unroll
        for (int i = 1; i < 12; ++i)
            if (bid >= BASE[i]) op = i;
        int idx = bid - BASE[op];
        if (op < 7) {
            int Nv = 0, ldt = 0;
            #pragma unroll
            for (int i = 0; i < 7; ++i)
                if (op == i) { Nv = NN[i]; ldt = LDT[i]; }
            int ncols = Nv / 32;
            int n0 = (idx % ncols) * 32, k0 = (idx / ncols) * 32;
            const float* W = a.src[op];
            u16* WT = a.dst[op];
            int tx = t & 31, ty = t >> 5;
            #pragma unroll
            for (int i = ty; i < 32; i += 8)
                tb[i][tx] = f2bf(W[(size_t)(k0 + i) * Nv + n0 + tx]);
            __syncthreads();
            #pragma unroll
            for (int i = ty; i < 32; i += 8)
                WT[(size_t)(n0 + i) * ldt + k0 + tx] = tb[tx][i];
        } else {
            int e = idx * 1024 + t * 4;
            float4 v = *(const float4*)(a.src[op] + e);
            ushort4 o;
            o.x = f2bf(v.x); o.y = f2bf(v.y); o.z = f2bf(v.z); o.w = f2bf(v.w);
            *(ushort4*)(a.dst[op] + e) = o;
        }
    }
}

// ---------------------------------------------------------------------------
// MFMA bf16 GEMM body (outbf is runtime; single call site per kernel)
// ---------------------------------------------------------------------------
template <int BM, int BN, int WM, int WN, bool SCATTER>
__device__ __forceinline__ void gemm_body(const u16* __restrict__ A, const u16* __restrict__ BT,
                                          const float* __restrict__ bias,
                                          void* __restrict__ Cout, int M, int N, int K,
                                          int bx, int by, bool outbf) {
    constexpr int MF = WM / 16, NF = WN / 16;
    constexpr int NWC = BN / WN;
    __shared__ u16 ldsA[BM][64];
    __shared__ u16 ldsB[BN][64];
    const int tid = threadIdx.x;
    const int lane = tid & 63;
    const int wv = tid >> 6;
    const int m0 = by * BM;
    const int n0 = bx * BN;
    const int wr = wv / NWC, wc = wv % NWC;
    const int srow = lane >> 3;
    const int sslot = lane & 7;

    f32x4 acc[MF][NF];
    #pragma unroll
    for (int i = 0; i < MF; ++i)
        #pragma unroll
        for (int j = 0; j < NF; ++j)
            #pragma unroll
            for (int r = 0; r < 4; ++r) acc[i][j][r] = 0.f;

    for (int k0 = 0; k0 < K; k0 += 64) {
        #pragma unroll
        for (int i = 0; i < BM / 32; ++i) {
            int R = wv * (BM / 4) + i * 8 + srow;
            int gm = m0 + R;
            gm = gm < M ? gm : M - 1;
            int s = sslot ^ (R & 7);
            ASYNC_COPY16(A + (size_t)gm * K + k0 + s * 8, &ldsA[wv * (BM / 4) + i * 8][0]);
        }
        #pragma unroll
        for (int i = 0; i < BN / 32; ++i) {
            int R = wv * (BN / 4) + i * 8 + srow;
            int s = sslot ^ (R & 7);
            ASYNC_COPY16(BT + (size_t)(n0 + R) * K + k0 + s * 8, &ldsB[wv * (BN / 4) + i * 8][0]);
        }
        __syncthreads();
        #pragma unroll
        for (int ks = 0; ks < 2; ++ks) {
            bf16x8 af[MF], bf[NF];
            int kg = ks * 4 + (lane >> 4);
            int rl = lane & 15;
            #pragma unroll
            for (int i = 0; i < MF; ++i) {
                int row = wr * WM + i * 16 + rl;
                af[i] = *(const bf16x8*)&ldsA[row][(kg ^ (row & 7)) * 8];
            }
            #pragma unroll
            for (int j = 0; j < NF; ++j) {
                int row = wc * WN + j * 16 + rl;
                bf[j] = *(const bf16x8*)&ldsB[row][(kg ^ (row & 7)) * 8];
            }
            #pragma unroll
            for (int i = 0; i < MF; ++i)
                #pragma unroll
                for (int j = 0; j < NF; ++j)
                    acc[i][j] = __builtin_amdgcn_mfma_f32_16x16x32_bf16(af[i], bf[j], acc[i][j], 0, 0, 0);
        }
        __syncthreads();
    }

    const int rl = lane & 15, rg = lane >> 4;
    #pragma unroll
    for (int i = 0; i < MF; ++i) {
        #pragma unroll
        for (int j = 0; j < NF; ++j) {
            int col = n0 + wc * WN + j * 16 + rl;
            float bv = bias[col];
            #pragma unroll
            for (int r = 0; r < 4; ++r) {
                int row = m0 + wr * WM + i * 16 + rg * 4 + r;
                if (row >= M) continue;
                float x = acc[i][j][r] + bv;
                if (SCATTER) {
                    int layer = col >> 10, blk = (col >> 9) & 1, head = (col >> 6) & 7, hd = col & 63;
                    int bb = row / ELEN, ll = row - bb * ELEN;
                    size_t oi = (((((size_t)layer * NBLOCKS + blk) * BATCH + bb) * NHEADS + head) * ELEN + ll) * 64 + hd;
                    ((float*)Cout)[oi] = x;
                } else if (outbf) {
                    ((u16*)Cout)[(size_t)row * N + col] = f2bf(x);
                } else {
                    ((float*)Cout)[(size_t)row * N + col] = x;
                }
            }
        }
    }
}

// ---------------------------------------------------------------------------
// 3) build: [0,1600) MBX gather-sum; [1600,1608) QB GEMM; [1608,1896) WC GEMM
// ---------------------------------------------------------------------------
__global__ __launch_bounds__(256) void build_kernel(
    const int* __restrict__ segcnt, const int* __restrict__ bucket,
    const int* __restrict__ uniq, const int* __restrict__ nuniq,
    const float* __restrict__ comp, const float* __restrict__ x, u16* __restrict__ MBX,
    const u16* __restrict__ TMEAN, const u16* __restrict__ CQT,
    const float* __restrict__ cq_b, u16* __restrict__ QB,
    const u16* __restrict__ KGT, const u16* __restrict__ W1f,
    const float* __restrict__ ZB, u16* __restrict__ WC) {
    int blk = blockIdx.x;
    if (blk >= NPOS) {
        const u16 *A, *BT;
        const float* bias;
        u16* C;
        int M, N, K, bx, by;
        if (blk >= NPOS + 8) {
            int i = blk - (NPOS + 8);
            A = KGT; BT = W1f; bias = ZB; C = WC;
            M = HDIM; N = 2304; K = HALF; bx = i % 36; by = i / 36;
        } else {
            A = TMEAN; BT = CQT; bias = cq_b; C = QB;
            M = BATCH; N = HDIM; K = HDIM; bx = blk - NPOS; by = 0;
        }
        gemm_body<64, 64, 32, 32, false>(A, BT, bias, C, M, N, K, bx, by, true);
        return;
    }
    int u = blk;
    int i = threadIdx.x;
    __shared__ float sc[NRELS * NBASES];
    if (i < NRELS * NBASES) sc[i] = comp[i];
    __syncthreads();
    u16* row = MBX + (size_t)u * 2304;
    int nu = *nuniq;
    if (u >= nu) {
        for (int b = 0; b < NBASES + 1; ++b) row[b * HALF + i] = 0;
        return;
    }
    float mr[NRELS];
    #pragma unroll
    for (int r = 0; r < NRELS; ++r) {
        int seg = u * NRELS + r;
        int c = segcnt[seg];
        int n = min(c, BCAP);
        float acc = 0.f;
        for (int e = 0; e < n; ++e) {
            int s = bucket[seg * BCAP + e];
            acc += x[(size_t)s * HALF + i];
        }
        mr[r] = acc * (1.f / fmaxf((float)c, 1.f));
    }
    #pragma unroll
    for (int b = 0; b < NBASES; ++b) {
        float a = 0.f;
        #pragma unroll
        for (int r = 0; r < NRELS; ++r) a += sc[r * NBASES + b] * mr[r];
        row[b * HALF + i] = f2bf(a);
    }
    row[NBASES * HALF + i] = f2bf(x[(size_t)uniq[u] * HALF + i]);
}

// ---------------------------------------------------------------------------
// 4) proj4: {KGU(200) | TXU(200) | IMU(200) | QP(25)} single call site
// ---------------------------------------------------------------------------
struct Proj4Args {
    const u16 *MBX, *WC, *TXIN, *TXT, *IMIN, *IMT, *QB, *SW;
    const float *biasC, *txb, *imb, *ZB;
    u16 *KGU, *TXU, *IMU;
    float* QP;
};
__global__ __launch_bounds__(256) void proj4_kernel(Proj4Args a) {
    int b = blockIdx.x;
    const u16 *A, *BT;
    const float* bias;
    void* C;
    int M, N, K, bx, by;
    bool obf;
    if (b < 200) {
        A = a.MBX; BT = a.WC; bias = a.biasC; C = a.KGU;
        M = NPOS; N = HDIM; K = 2304; bx = b % 8; by = b / 8; obf = true;
    } else if (b < 400) {
        int i = b - 200;
        A = a.TXIN; BT = a.TXT; bias = a.txb; C = a.TXU;
        M = NPOS; N = HDIM; K = TXTD; bx = i % 8; by = i / 8; obf = true;
    } else if (b < 600) {
        int i = b - 400;
        A = a.IMIN; BT = a.IMT; bias = a.imb; C = a.IMU;
        M = NPOS; N = HDIM; K = TXTD; bx = i % 8; by = i / 8; obf = true;
    } else {
        A = a.QB; BT = a.SW; bias = a.ZB; C = a.QP;
        M = BATCH; N = 1600; K = HDIM; bx = b - 600; by = 0; obf = false;
    }
    gemm_body<64, 64, 32, 32, false>(A, BT, bias, C, M, N, K, bx, by, obf);
}

// ---------------------------------------------------------------------------
// 5) tail: fusion + P1 + H fused. 16 rows/block, 100 blocks, 4 waves.
// ---------------------------------------------------------------------------
__global__ __launch_bounds__(256) void tail_kernel(
    const int* __restrict__ eid, const int* __restrict__ map,
    const u16* __restrict__ KGU, const u16* __restrict__ IMU, const u16* __restrict__ TXU,
    const float* __restrict__ qp,
    const u16* __restrict__ W1T, const float* __restrict__ pp1_b1,
    const u16* __restrict__ W2T, const float* __restrict__ pp1_b2,
    u16* __restrict__ Hh) {
    __shared__ u16 FUS[16][520];
    __shared__ u16 P1s[16][264];
    const int bm0 = blockIdx.x * 16;
    const int lane = threadIdx.x & 63;
    const int wv = threadIdx.x >> 6;

    // ---- phase A: fusion (4 rows per wave) ----
    for (int rr = wv; rr < 16; rr += 4) {
        int bl = bm0 + rr;
        int b = bl / ELEN;
        int u = map[eid[bl]];
        const u16* kg = KGU + (size_t)u * HDIM;
        const u16* im = IMU + (size_t)u * HDIM;
        const u16* tx = TXU + (size_t)u * HDIM;
        const float* qrow = qp + (size_t)b * 1600;
        float pkg = 0.f, pim = 0.f, ptx = 0.f;
        for (int e = lane; e < HDIM; e += 64) {
            pkg += bf2f(kg[e]) * qrow[e];
            pim += bf2f(im[e]) * qrow[512 + e];
            ptx += bf2f(tx[e]) * qrow[1024 + e];
        }
        #pragma unroll
        for (int off = 32; off; off >>= 1) {
            pkg += __shfl_down(pkg, off);
            pim += __shfl_down(pim, off);
            ptx += __shfl_down(ptx, off);
        }
        float w0, w1, w2;
        if (lane == 0) {
            float av = pkg + qrow[1536];
            float c1 = pim + qrow[1537];
            float c2 = ptx + qrow[1538];
            float mx = fmaxf(av, fmaxf(c1, c2));
            float ea = __expf(av - mx), eb = __expf(c1 - mx), ec = __expf(c2 - mx);
            float inv = 1.f / (ea + eb + ec);
            w0 = ea * inv; w1 = eb * inv; w2 = ec * inv;
        }
        w0 = __shfl(w0, 0); w1 = __shfl(w1, 0); w2 = __shfl(w2, 0);
        for (int e = lane; e < HDIM; e += 64) {
            float v = w0 * bf2f(kg[e]) + w1 * bf2f(im[e]) + w2 * bf2f(tx[e]);
            FUS[rr][e] = f2bf(v);
        }
    }
    __syncthreads();

    // ---- phase B: P1[16][256] = relu(FUS @ W1T^T + b1); wave covers 64 cols ----
    {
        const int rl = lane & 15;
        const int kgrp = lane >> 4;
        f32x4 acc[4];
        #pragma unroll
        for (int j = 0; j < 4; ++j)
            #pragma unroll
            for (int r = 0; r < 4; ++r) acc[j][r] = 0.f;
        for (int kk = 0; kk < 512; kk += 32) {
            int k8 = kk + kgrp * 8;
            bf16x8 af = *(const bf16x8*)&FUS[rl][k8];
            bf16x8 bf[4];
            #pragma unroll
            for (int j = 0; j < 4; ++j) {
                int n = wv * 64 + j * 16 + rl;
                bf[j] = *(const bf16x8*)&W1T[(size_t)n * 512 + k8];
            }
            #pragma unroll
            for (int j = 0; j < 4; ++j)
                acc[j] = __builtin_amdgcn_mfma_f32_16x16x32_bf16(af, bf[j], acc[j], 0, 0, 0);
        }
        const int rg = lane >> 4;
        #pragma unroll
        for (int j = 0; j < 4; ++j) {
            int col = wv * 64 + j * 16 + rl;
            float bv = pp1_b1[col];
            #pragma unroll
            for (int r = 0; r < 4; ++r) {
                int row = rg * 4 + r;
                P1s[row][col] = f2bf(fmaxf(acc[j][r] + bv, 0.f));
            }
        }
    }
    __syncthreads();

    // ---- phase C: H[16][512] = P1 @ W2T^T + b2 + FUS; wave covers 128 cols ----
    {
        const int rl = lane & 15;
        const int kgrp = lane >> 4;
        f32x4 acc[8];
        #pragma unroll
        for (int j = 0; j < 8; ++j)
            #pragma unroll
            for (int r = 0; r < 4; ++r) acc[j][r] = 0.f;
        for (int kk = 0; kk < 256; kk += 32) {
            int k8 = kk + kgrp * 8;
            bf16x8 af = *(const bf16x8*)&P1s[rl][k8];
            bf16x8 bf[8];
            #pragma unroll
            for (int j = 0; j < 8; ++j) {
                int n = wv * 128 + j * 16 + rl;
                bf[j] = *(const bf16x8*)&W2T[(size_t)n * 256 + k8];
            }
            #pragma unroll
            for (int j = 0; j < 8; ++j)
                acc[j] = __builtin_amdgcn_mfma_f32_16x16x32_bf16(af, bf[j], acc[j], 0, 0, 0);
        }
        const int rg = lane >> 4;
        #pragma unroll
        for (int j = 0; j < 8; ++j) {
            int col = wv * 128 + j * 16 + rl;
            float bv = pp1_b2[col];
            #pragma unroll
            for (int r = 0; r < 4; ++r) {
                int row = rg * 4 + r;
                float v = acc[j][r] + bv + bf2f(FUS[row][col]);
                Hh[(size_t)(bm0 + row) * HDIM + col] = f2bf(v);
            }
        }
    }
}

// ---------------------------------------------------------------------------
// 6) pp2 scatter GEMM
// ---------------------------------------------------------------------------
__global__ __launch_bounds__(256)
void pp2_kernel(const u16* __restrict__ A, const u16* __restrict__ BT,
                const float* __restrict__ bias, void* __restrict__ Cout,
                int M, int N, int K) {
    gemm_body<128, 128, 64, 64, true>(A, BT, bias, Cout, M, N, K, blockIdx.x, blockIdx.y, false);
}

// ---------------------------------------------------------------------------
extern "C" void kernel_launch(void* const* d_in, const int* in_sizes, int n_in,
                              void* d_out, int out_size, void* d_ws, size_t ws_size,
                              hipStream_t stream) {
    const int* entity_ids = (const int*)d_in[0];
    const float* token_embeds = (const float*)d_in[1];
    const int* edge_index = (const int*)d_in[2];
    const int* edge_type = (const int*)d_in[3];
    const float* node_embeds = (const float*)d_in[4];
    const float* rgcn_basis = (const float*)d_in[5];
    const float* rgcn_comp = (const float*)d_in[6];
    const float* rgcn_root = (const float*)d_in[7];
    const float* rgcn_bias = (const float*)d_in[8];
    const float* kg_proj_w = (const float*)d_in[9];
    const float* kg_proj_b = (const float*)d_in[10];
    const float* text_proj_w = (const float*)d_in[11];
    const float* text_proj_b = (const float*)d_in[12];
    const float* image_proj_w = (const float*)d_in[13];
    const float* image_proj_b = (const float*)d_in[14];
    const float* cq_w = (const float*)d_in[15];
    const float* cq_b = (const float*)d_in[16];
    const float* kgk_w = (const float*)d_in[17];
    const float* imk_w = (const float*)d_in[19];
    const float* txk_w = (const float*)d_in[21];
    const float* pp1_w1 = (const float*)d_in[23];
    const float* pp1_b1 = (const float*)d_in[24];
    const float* pp1_w2 = (const float*)d_in[25];
    const float* pp1_b2 = (const float*)d_in[26];
    const float* pp2_w = (const float*)d_in[27];
    const float* pp2_b = (const float*)d_in[28];
    const float* text_init = (const float*)d_in[29];
    const float* image_init = (const float*)d_in[30];

    const int E = in_sizes[3];  // 500000

    size_t off = 0;
    auto alloc = [&](size_t bytes) { size_t o = off; off += (bytes + 255) & ~(size_t)255; return o; };
    char* ws = (char*)d_ws;
    size_t map_o  = alloc((size_t)NENTS * 4);
    size_t nun_o  = alloc(4);
    size_t unq_o  = alloc((size_t)NPOS * 4);
    size_t scnt_o = alloc((size_t)NSEG * 4);
    size_t bkt_o  = alloc((size_t)NSEG * BCAP * 4);
    size_t mbx_o  = alloc((size_t)NPOS * 2304 * 2);
    size_t w1f_o  = alloc((size_t)2304 * HALF * 2);
    size_t wc_o   = alloc((size_t)HDIM * 2304 * 2);
    size_t bc_o   = alloc((size_t)HDIM * 4);
    size_t kgt_o  = alloc((size_t)HDIM * HALF * 2);
    size_t kgu_o  = alloc((size_t)NPOS * HDIM * 2);
    size_t txin_o = alloc((size_t)NPOS * TXTD * 2);
    size_t imin_o = alloc((size_t)NPOS * TXTD * 2);
    size_t txt_o  = alloc((size_t)HDIM * TXTD * 2);
    size_t imt_o  = alloc((size_t)HDIM * TXTD * 2);
    size_t txu_o  = alloc((size_t)NPOS * HDIM * 2);
    size_t imu_o  = alloc((size_t)NPOS * HDIM * 2);
    size_t tm_o   = alloc((size_t)BATCH * HDIM * 2);
    size_t qb_o   = alloc((size_t)BATCH * HDIM * 2);
    size_t cqt_o  = alloc((size_t)HDIM * HDIM * 2);
    size_t sw_o   = alloc((size_t)1600 * HDIM * 2);
    size_t qp_o   = alloc((size_t)BATCH * 1600 * 4);
    size_t zb_o   = alloc((size_t)2304 * 4);
    size_t w1t_o  = alloc((size_t)HALF * HDIM * 2);
    size_t w2t_o  = alloc((size_t)HDIM * HALF * 2);
    size_t h_o    = alloc((size_t)NPOS * HDIM * 2);
    size_t pp2t_o = alloc((size_t)12288 * HDIM * 2);
    if (off > ws_size) return;

    int* map = (int*)(ws + map_o);
    int* nuniq = (int*)(ws + nun_o);
    int* uniq = (int*)(ws + unq_o);
    int* segcnt = (int*)(ws + scnt_o);
    int* bucket = (int*)(ws + bkt_o);
    u16* MBX = (u16*)(ws + mbx_o);
    u16* W1f = (u16*)(ws + w1f_o);
    u16* WC  = (u16*)(ws + wc_o);
    float* biasC = (float*)(ws + bc_o);
    u16* KGT = (u16*)(ws + kgt_o);
    u16* KGU = (u16*)(ws + kgu_o);
    u16* TXIN = (u16*)(ws + txin_o);
    u16* IMIN = (u16*)(ws + imin_o);
    u16* TXT = (u16*)(ws + txt_o);
    u16* IMT = (u16*)(ws + imt_o);
    u16* TXU = (u16*)(ws + txu_o);
    u16* IMU = (u16*)(ws + imu_o);
    u16* TMEAN = (u16*)(ws + tm_o);
    u16* QB  = (u16*)(ws + qb_o);
    u16* CQT = (u16*)(ws + cqt_o);
    u16* SW  = (u16*)(ws + sw_o);
    float* QP  = (float*)(ws + qp_o);
    float* ZB  = (float*)(ws + zb_o);
    u16* W1T = (u16*)(ws + w1t_o);
    u16* W2T = (u16*)(ws + w2t_o);
    u16* Hh  = (u16*)(ws + h_o);
    u16* PP2T = (u16*)(ws + pp2t_o);
    float* OUT = (float*)d_out;

    // 1) init (+ biasC from fp32 inputs)
    init_kernel<<<130, 256, 0, stream>>>(map, segcnt, nuniq, ZB,
                                         (const float*)d_in[18], (const float*)d_in[20],
                                         (const float*)d_in[22], SW,
                                         rgcn_bias, kg_proj_w, kg_proj_b, biasC,
                                         OUT + (out_size - 1));
    // 2) dedup
    dedup_kernel<<<(NPOS + 255) / 256, 256, 0, stream>>>(entity_ids, map, uniq, nuniq);
    // 3) midprep: tokmean | gather | edge-filter | weight-prep
    PrepArgs pa;
    pa.src[0] = kg_proj_w;    pa.dst[0] = KGT;   // trans
    pa.src[1] = text_proj_w;  pa.dst[1] = TXT;
    pa.src[2] = image_proj_w; pa.dst[2] = IMT;
    pa.src[3] = pp1_w1;       pa.dst[3] = W1T;
    pa.src[4] = pp1_w2;       pa.dst[4] = W2T;
    pa.src[5] = pp2_w;        pa.dst[5] = PP2T;
    pa.src[6] = cq_w;         pa.dst[6] = CQT;
    pa.src[7] = rgcn_basis;   pa.dst[7] = W1f;   // conv
    pa.src[8] = rgcn_root;    pa.dst[8] = W1f + (size_t)2048 * HALF;
    pa.src[9] = kgk_w;        pa.dst[9] = SW;
    pa.src[10] = imk_w;       pa.dst[10] = SW + (size_t)HDIM * HDIM;
    pa.src[11] = txk_w;       pa.dst[11] = SW + (size_t)2 * HDIM * HDIM;
    midprep_kernel<<<9920, 256, 0, stream>>>(token_embeds, TMEAN,
                                             uniq, nuniq, text_init, image_init, TXIN, IMIN,
                                             edge_index, edge_type, map, segcnt, bucket, E, pa);
    // 4) build MBX + QB GEMM + WC GEMM
    build_kernel<<<NPOS + 8 + 288, 256, 0, stream>>>(segcnt, bucket, uniq, nuniq, rgcn_comp,
                                                     node_embeds, MBX, TMEAN, CQT, cq_b, QB,
                                                     KGT, W1f, ZB, WC);
    // 5) proj4: KGU | TXU | IMU | QP
    Proj4Args p4;
    p4.MBX = MBX; p4.WC = WC; p4.biasC = biasC; p4.KGU = KGU;
    p4.TXIN = TXIN; p4.TXT = TXT; p4.txb = text_proj_b; p4.TXU = TXU;
    p4.IMIN = IMIN; p4.IMT = IMT; p4.imb = image_proj_b; p4.IMU = IMU;
    p4.QB = QB; p4.SW = SW; p4.ZB = ZB; p4.QP = QP;
    proj4_kernel<<<625, 256, 0, stream>>>(p4);
    // 6) tail: fusion + P1 + H
    tail_kernel<<<NPOS / 16, 256, 0, stream>>>(entity_ids, map, KGU, IMU, TXU, QP,
                                               W1T, pp1_b1, W2T, pp1_b2, Hh);
    // 7) OUT = scatter(H @ pp2_w + pp2_b)
    pp2_kernel<<<dim3(12288 / 128, (NPOS + 127) / 128), 256, 0, stream>>>(
        Hh, PP2T, pp2_b, OUT, NPOS, 12288, HDIM);
}